// Round 5
// baseline (427.674 us; speedup 1.0000x reference)
//
#include <hip/hip_runtime.h>
#include <math.h>

#define N_NODES 50000
#define N_EDGES 1600000
#define D_IN 128
#define D_OUT 32
#define ALPHA 0.2f

#define NB  2000     // buckets (NB * RPB == N_NODES exactly)
#define RPB 25       // rows per bucket
#define CAP 1024     // slots per bucket (mean 800, sigma ~28 -> 8 sigma margin)
#define PT  16       // edges per thread in k_part
#define PB  1024     // threads per block in k_part
#define EB  (PT * PB) // 16384 edges per block
#define CHUNK 256    // edges staged per k_bucket inner chunk
#define ASTR 33      // padded acc row stride (bank-conflict break)

// Monotone float<->int key (involution). Works with signed atomicMin/Max.
__device__ __forceinline__ int enc_f(float x) {
    int i = __float_as_int(x);
    return i >= 0 ? i : (i ^ 0x7fffffff);
}
__device__ __forceinline__ float dec_f(int k) {
    return __int_as_float(k >= 0 ? k : (k ^ 0x7fffffff));
}

// Kernel A: X_prime = X @ W  [N,32], s0 = Xp.a0, s1 = Xp.a1.
// 8 nodes per 256-thread block; 32 lanes per node (one per output dim).
// Block 0 also zeroes the bucket counters + minmax slots (stream-ordered).
__global__ __launch_bounds__(256) void k_xw(const float* __restrict__ X,
                                            const float* __restrict__ W,
                                            const float* __restrict__ a0,
                                            const float* __restrict__ a1,
                                            float* __restrict__ Xp,
                                            float* __restrict__ s0,
                                            float* __restrict__ s1,
                                            int* __restrict__ minmax,
                                            int* __restrict__ gcount) {
    __shared__ float Wl[D_IN * D_OUT]; // 16 KiB
    __shared__ float Xl[8 * D_IN];     // 4 KiB
    const int tid = threadIdx.x;
    if (blockIdx.x == 0) {
        if (tid == 0) {
            minmax[0] = 0x7fffffff; // running min key
            minmax[1] = 0x80000000; // running max key
        }
        for (int i = tid; i < NB; i += 256) gcount[i] = 0;
    }
    for (int i = tid; i < D_IN * D_OUT; i += 256) Wl[i] = W[i];
    const int node0 = blockIdx.x * 8; // 50000/8 = 6250 blocks, no tail
    for (int i = tid; i < 8 * D_IN; i += 256) Xl[i] = X[(size_t)node0 * D_IN + i];
    __syncthreads();

    const int g = tid >> 5;   // node group within block
    const int t = tid & 31;   // output dim
    const int node = node0 + g;
    const float* xr = &Xl[g * D_IN];
    float acc = 0.f;
#pragma unroll
    for (int k = 0; k < D_IN; ++k) acc += xr[k] * Wl[k * D_OUT + t];
    Xp[(size_t)node * D_OUT + t] = acc;

    float v0 = acc * a0[t];
    float v1 = acc * a1[t];
#pragma unroll
    for (int m = 16; m >= 1; m >>= 1) {
        v0 += __shfl_xor(v0, m);
        v1 += __shfl_xor(v1, m);
    }
    if (t == 0) { s0[node] = v0; s1[node] = v1; }
}

// Kernel B: bucket-partition edges + global min/max.
// Per block: LDS histogram over NB buckets -> one global atomicAdd per
// bucket reserves a contiguous range in that bucket's fixed region ->
// 8B entries {lr<<16|col, leaky_score} written in per-block bursts.
__global__ __launch_bounds__(PB) void k_part(const int* __restrict__ row,
                                             const int* __restrict__ col,
                                             const float* __restrict__ s0,
                                             const float* __restrict__ s1,
                                             int* __restrict__ gcount,
                                             int* __restrict__ minmax,
                                             uint2* __restrict__ gEdges) {
    __shared__ int hist[NB]; // 8 KB
    __shared__ int lcur[NB]; // 8 KB
    __shared__ int smn[PB / 64], smx[PB / 64];
    const int t = threadIdx.x;
    for (int i = t; i < NB; i += PB) hist[i] = 0;
    __syncthreads();

    const int base = blockIdx.x * EB;
    unsigned px[PT]; // (b:11 | lr:5 | col:16)
    float    fa[PT]; // leaky-relu'd score
    int cnt = 0;
    int kmin = 0x7fffffff, kmax = 0x80000000;
#pragma unroll
    for (int i = 0; i < PT; ++i) {
        const int e = base + i * PB + t;
        if (e >= N_EDGES) break; // e increases with i
        const int r = row[e];
        const int c = col[e];
        float a = s0[r] + s1[c];
        a = a > 0.f ? a : ALPHA * a;
        const int k = enc_f(a);
        kmin = min(kmin, k);
        kmax = max(kmax, k);
        const unsigned b = (unsigned)r / RPB;
        const unsigned lr = (unsigned)r - b * RPB;
        px[cnt] = (b << 21) | (lr << 16) | (unsigned)c;
        fa[cnt] = a;
        ++cnt;
        atomicAdd(&hist[b], 1);
    }
    __syncthreads();
    for (int i = t; i < NB; i += PB) {
        const int h = hist[i];
        lcur[i] = h > 0 ? atomicAdd(&gcount[i], h) : 0;
    }
    __syncthreads();
    for (int j = 0; j < cnt; ++j) {
        const unsigned p = px[j];
        const unsigned b = p >> 21;
        const int pos = atomicAdd(&lcur[b], 1);
        gEdges[(size_t)b * CAP + pos] =
            make_uint2(p & 0x1FFFFFu, (unsigned)__float_as_int(fa[j]));
    }
    // block min/max reduction -> 2 global atomics
#pragma unroll
    for (int m = 32; m >= 1; m >>= 1) {
        kmin = min(kmin, __shfl_xor(kmin, m));
        kmax = max(kmax, __shfl_xor(kmax, m));
    }
    const int wave = t >> 6;
    if ((t & 63) == 0) { smn[wave] = kmin; smx[wave] = kmax; }
    __syncthreads();
    if (t == 0) {
#pragma unroll
        for (int w = 1; w < PB / 64; ++w) {
            kmin = min(kmin, smn[w]);
            kmax = max(kmax, smx[w]);
        }
        atomicMin(&minmax[0], kmin);
        atomicMax(&minmax[1], kmax);
    }
}

// Kernel C: one block per bucket (2000 blocks).
// Per 256-edge chunk: bulk-stage entries into LDS (1 coalesced 8B load per
// thread), then 32 groups x 8 lanes process 8 edges each, fully unrolled:
// 8 independent float4 Xp gathers in flight per group (8KB/wave MLP),
// LDS float atomics into a stride-33-padded accumulator.
__global__ __launch_bounds__(256, 4) void k_bucket(const int* __restrict__ gcount,
                                                   const uint2* __restrict__ gEdges,
                                                   const float* __restrict__ Xp,
                                                   const int* __restrict__ minmax,
                                                   float* __restrict__ out) {
    __shared__ float acc[RPB * ASTR]; // 3.3 KB, padded stride
    __shared__ float wsum[RPB];
    __shared__ unsigned scol[CHUNK];  // staged (lr<<16|col)
    __shared__ float ssc[CHUNK];      // staged leaky score
    const int b = blockIdx.x;
    const int t = threadIdx.x;
    for (int i = t; i < RPB * ASTR; i += 256) acc[i] = 0.f;
    if (t < RPB) wsum[t] = 0.f;
    const float mn = dec_f(minmax[0]);
    const float mx = dec_f(minmax[1]);
    const float inv = 1.0f / (mx - mn);
    const int cnt = gcount[b];
    const uint2* eb = gEdges + (size_t)b * CAP;
    const int g = t >> 3;  // group 0..31
    const int k = t & 7;   // lane in group; handles dims [4k, 4k+4)
    __syncthreads();

    for (int base = 0; base < cnt; base += CHUNK) {
        const int m = min(CHUNK, cnt - base);
        if (t < m) {
            const uint2 e = eb[base + t];
            scol[t] = e.x;
            ssc[t] = __int_as_float(e.y);
        }
        __syncthreads();
        if (m == CHUNK) { // full chunk: group g owns edges [8g, 8g+8)
            float4 x[8];
            unsigned lr[8];
            float w[8];
#pragma unroll
            for (int j = 0; j < 8; ++j) {
                const unsigned p = scol[g * 8 + j];
                lr[j] = p >> 16;
                x[j] = *(const float4*)&Xp[(size_t)(p & 0xFFFFu) * D_OUT + 4 * k];
                w[j] = __expf((ssc[g * 8 + j] - mn) * inv);
            }
#pragma unroll
            for (int j = 0; j < 8; ++j) {
                float* ar = &acc[lr[j] * ASTR + 4 * k];
                atomicAdd(&ar[0], w[j] * x[j].x);
                atomicAdd(&ar[1], w[j] * x[j].y);
                atomicAdd(&ar[2], w[j] * x[j].z);
                atomicAdd(&ar[3], w[j] * x[j].w);
                if (k == 0) atomicAdd(&wsum[lr[j]], w[j]);
            }
        } else {          // tail chunk: strided, guarded
            for (int j = g; j < m; j += 32) {
                const unsigned p = scol[j];
                const unsigned lr0 = p >> 16;
                const float4 xv = *(const float4*)&Xp[(size_t)(p & 0xFFFFu) * D_OUT + 4 * k];
                const float w0 = __expf((ssc[j] - mn) * inv);
                float* ar = &acc[lr0 * ASTR + 4 * k];
                atomicAdd(&ar[0], w0 * xv.x);
                atomicAdd(&ar[1], w0 * xv.y);
                atomicAdd(&ar[2], w0 * xv.z);
                atomicAdd(&ar[3], w0 * xv.w);
                if (k == 0) atomicAdd(&wsum[lr0], w0);
            }
        }
        __syncthreads();
    }
    // NB*RPB == N_NODES exactly -> no row guard needed
    const int r0 = b * RPB;
    for (int i = t; i < RPB * D_OUT; i += 256) {
        out[(size_t)r0 * D_OUT + i] = acc[(i >> 5) * ASTR + (i & 31)] / wsum[i >> 5];
    }
}

extern "C" void kernel_launch(void* const* d_in, const int* in_sizes, int n_in,
                              void* d_out, int out_size, void* d_ws, size_t ws_size,
                              hipStream_t stream) {
    const float* X  = (const float*)d_in[0];
    const float* W  = (const float*)d_in[1];
    const float* a0 = (const float*)d_in[2];
    const float* a1 = (const float*)d_in[3];
    const int* row  = (const int*)d_in[4];
    const int* col  = (const int*)d_in[5];
    float* out = (float*)d_out;

    // Workspace layout (4B units):
    // [minmax: 64][gcount: 2048][s0: 50048][s1: 50048][Xp: 1.6M][gEdges: NB*CAP uint2]
    float* ws = (float*)d_ws;
    int*   minmax = (int*)ws;
    int*   gcount = (int*)(ws + 64);
    float* s0 = ws + 64 + 2048;
    float* s1 = s0 + 50048;
    float* Xp = s1 + 50048;  // 16B-aligned offset (102208 * 4B)
    uint2* gEdges = (uint2*)(Xp + (size_t)N_NODES * D_OUT);

    k_xw<<<N_NODES / 8, 256, 0, stream>>>(X, W, a0, a1, Xp, s0, s1, minmax, gcount);
    k_part<<<(N_EDGES + EB - 1) / EB, PB, 0, stream>>>(row, col, s0, s1, gcount,
                                                       minmax, gEdges);
    k_bucket<<<NB, 256, 0, stream>>>(gcount, gEdges, Xp, minmax, out);
}

// Round 6
// 183.978 us; speedup vs baseline: 2.3246x; 2.3246x over previous
//
#include <hip/hip_runtime.h>
#include <math.h>

#define N_NODES 50000
#define N_EDGES 1600000
#define D_IN 128
#define D_OUT 32
#define ALPHA 0.2f

#define NB  2000     // buckets (NB * RPB == N_NODES exactly)
#define RPB 25       // rows per bucket
#define CAP 1024     // slots per bucket (mean 800, sigma ~28 -> 8 sigma margin)
#define PT  16       // edges per thread in k_part
#define PB  1024     // threads per block in k_part
#define EB  (PT * PB) // 16384 edges per block

// Monotone float<->int key (involution). Works with signed atomicMin/Max.
__device__ __forceinline__ int enc_f(float x) {
    int i = __float_as_int(x);
    return i >= 0 ? i : (i ^ 0x7fffffff);
}
__device__ __forceinline__ float dec_f(int k) {
    return __int_as_float(k >= 0 ? k : (k ^ 0x7fffffff));
}

// Kernel A: X_prime = X @ W  [N,32], s0 = Xp.a0, s1 = Xp.a1.
// 8 nodes per 256-thread block; 32 lanes per node (one per output dim).
// Block 0 also zeroes the bucket counters + minmax slots (stream-ordered).
__global__ __launch_bounds__(256) void k_xw(const float* __restrict__ X,
                                            const float* __restrict__ W,
                                            const float* __restrict__ a0,
                                            const float* __restrict__ a1,
                                            float* __restrict__ Xp,
                                            float* __restrict__ s0,
                                            float* __restrict__ s1,
                                            int* __restrict__ minmax,
                                            int* __restrict__ gcount) {
    __shared__ float Wl[D_IN * D_OUT]; // 16 KiB
    __shared__ float Xl[8 * D_IN];     // 4 KiB
    const int tid = threadIdx.x;
    if (blockIdx.x == 0) {
        if (tid == 0) {
            minmax[0] = 0x7fffffff; // running min key
            minmax[1] = 0x80000000; // running max key
        }
        for (int i = tid; i < NB; i += 256) gcount[i] = 0;
    }
    for (int i = tid; i < D_IN * D_OUT; i += 256) Wl[i] = W[i];
    const int node0 = blockIdx.x * 8; // 50000/8 = 6250 blocks, no tail
    for (int i = tid; i < 8 * D_IN; i += 256) Xl[i] = X[(size_t)node0 * D_IN + i];
    __syncthreads();

    const int g = tid >> 5;   // node group within block
    const int t = tid & 31;   // output dim
    const int node = node0 + g;
    const float* xr = &Xl[g * D_IN];
    float acc = 0.f;
#pragma unroll
    for (int k = 0; k < D_IN; ++k) acc += xr[k] * Wl[k * D_OUT + t];
    Xp[(size_t)node * D_OUT + t] = acc;

    float v0 = acc * a0[t];
    float v1 = acc * a1[t];
#pragma unroll
    for (int m = 16; m >= 1; m >>= 1) {
        v0 += __shfl_xor(v0, m);
        v1 += __shfl_xor(v1, m);
    }
    if (t == 0) { s0[node] = v0; s1[node] = v1; }
}

// Kernel B: bucket-partition edges + global min/max.
// Per block: LDS histogram over NB buckets -> one global atomicAdd per
// bucket reserves a contiguous range in that bucket's fixed region ->
// 8B entries {lr<<16|col, leaky_score} written in per-block bursts.
__global__ __launch_bounds__(PB) void k_part(const int* __restrict__ row,
                                             const int* __restrict__ col,
                                             const float* __restrict__ s0,
                                             const float* __restrict__ s1,
                                             int* __restrict__ gcount,
                                             int* __restrict__ minmax,
                                             uint2* __restrict__ gEdges) {
    __shared__ int hist[NB]; // 8 KB
    __shared__ int lcur[NB]; // 8 KB
    __shared__ int smn[PB / 64], smx[PB / 64];
    const int t = threadIdx.x;
    for (int i = t; i < NB; i += PB) hist[i] = 0;
    __syncthreads();

    const int base = blockIdx.x * EB;
    unsigned px[PT]; // (b:11 | lr:5 | col:16)
    float    fa[PT]; // leaky-relu'd score
    int cnt = 0;
    int kmin = 0x7fffffff, kmax = 0x80000000;
#pragma unroll
    for (int i = 0; i < PT; ++i) {
        const int e = base + i * PB + t;
        if (e >= N_EDGES) break; // e increases with i
        const int r = row[e];
        const int c = col[e];
        float a = s0[r] + s1[c];
        a = a > 0.f ? a : ALPHA * a;
        const int k = enc_f(a);
        kmin = min(kmin, k);
        kmax = max(kmax, k);
        const unsigned b = (unsigned)r / RPB;
        const unsigned lr = (unsigned)r - b * RPB;
        px[cnt] = (b << 21) | (lr << 16) | (unsigned)c;
        fa[cnt] = a;
        ++cnt;
        atomicAdd(&hist[b], 1);
    }
    __syncthreads();
    for (int i = t; i < NB; i += PB) {
        const int h = hist[i];
        lcur[i] = h > 0 ? atomicAdd(&gcount[i], h) : 0;
    }
    __syncthreads();
    for (int j = 0; j < cnt; ++j) {
        const unsigned p = px[j];
        const unsigned b = p >> 21;
        const int pos = atomicAdd(&lcur[b], 1);
        gEdges[(size_t)b * CAP + pos] =
            make_uint2(p & 0x1FFFFFu, (unsigned)__float_as_int(fa[j]));
    }
    // block min/max reduction -> 2 global atomics
#pragma unroll
    for (int m = 32; m >= 1; m >>= 1) {
        kmin = min(kmin, __shfl_xor(kmin, m));
        kmax = max(kmax, __shfl_xor(kmax, m));
    }
    const int wave = t >> 6;
    if ((t & 63) == 0) { smn[wave] = kmin; smx[wave] = kmax; }
    __syncthreads();
    if (t == 0) {
#pragma unroll
        for (int w = 1; w < PB / 64; ++w) {
            kmin = min(kmin, smn[w]);
            kmax = max(kmax, smx[w]);
        }
        atomicMin(&minmax[0], kmin);
        atomicMax(&minmax[1], kmax);
    }
}

// Kernel C: one block per bucket (2000 blocks). ATOMIC-FREE accumulation:
// 1) stage bucket's entries into registers (<=4/thread), LDS counting-sort
//    by local row (25 bins; only ~1.6K cheap int LDS atomics per block),
//    computing exp(minmaxnorm) ONCE per edge at scatter time;
// 2) 8 row-processors x 32 lanes walk each row's contiguous segment,
//    accumulating in registers (2-way unrolled independent chains), one
//    coalesced 128B Xp gather per edge; write out = acc/wsum directly.
__global__ __launch_bounds__(256, 8) void k_bucket(const int* __restrict__ gcount,
                                                   const uint2* __restrict__ gEdges,
                                                   const float* __restrict__ Xp,
                                                   const int* __restrict__ minmax,
                                                   float* __restrict__ out) {
    __shared__ int hist[32];
    __shared__ int off[32];   // 26 used
    __shared__ int cur[32];
    __shared__ int   scol[CAP];  // sorted col (4 KB)
    __shared__ float sw[CAP];    // sorted weight exp(...) (4 KB)
    const int b = blockIdx.x;
    const int t = threadIdx.x;
    const float mn = dec_f(minmax[0]);
    const float mx = dec_f(minmax[1]);
    const float inv = 1.0f / (mx - mn);
    const int cnt = min(gcount[b], CAP);
    const uint2* eb = gEdges + (size_t)b * CAP;

    // stage into registers + histogram
    unsigned rc[4];
    float ra[4];
    int n = 0;
    if (t < 32) hist[t] = 0;
    __syncthreads();
    for (int i = t; i < cnt; i += 256) {
        const uint2 e = eb[i];
        rc[n] = e.x;
        ra[n] = __int_as_float(e.y);
        ++n;
    }
    for (int j = 0; j < n; ++j) atomicAdd(&hist[rc[j] >> 16], 1);
    __syncthreads();
    if (t == 0) {
        int run = 0;
#pragma unroll
        for (int r = 0; r < RPB; ++r) { off[r] = run; run += hist[r]; }
        off[RPB] = run;
    }
    __syncthreads();
    if (t < RPB) cur[t] = off[t];
    __syncthreads();
    for (int j = 0; j < n; ++j) {
        const int lr = rc[j] >> 16;
        const int p = atomicAdd(&cur[lr], 1);
        scol[p] = rc[j] & 0xFFFF;
        sw[p] = __expf((ra[j] - mn) * inv);
    }
    __syncthreads();

    // row processing: 8 processors x 32 lanes, register accumulation
    const int proc = t >> 5;  // 0..7
    const int d = t & 31;     // output dim
    for (int lr = proc; lr < RPB; lr += 8) {
        const int s = off[lr];
        const int e2 = off[lr + 1];
        float acc0 = 0.f, acc1 = 0.f, ws0 = 0.f, ws1 = 0.f;
        int i = s;
        for (; i + 1 < e2; i += 2) {
            const int c0 = scol[i];
            const int c1 = scol[i + 1];
            const float w0 = sw[i];
            const float w1 = sw[i + 1];
            acc0 += w0 * Xp[(size_t)c0 * D_OUT + d];
            acc1 += w1 * Xp[(size_t)c1 * D_OUT + d];
            ws0 += w0;
            ws1 += w1;
        }
        if (i < e2) {
            const float w0 = sw[i];
            acc0 += w0 * Xp[(size_t)scol[i] * D_OUT + d];
            ws0 += w0;
        }
        const int r = b * RPB + lr;
        out[(size_t)r * D_OUT + d] = (acc0 + acc1) / (ws0 + ws1);
    }
}

extern "C" void kernel_launch(void* const* d_in, const int* in_sizes, int n_in,
                              void* d_out, int out_size, void* d_ws, size_t ws_size,
                              hipStream_t stream) {
    const float* X  = (const float*)d_in[0];
    const float* W  = (const float*)d_in[1];
    const float* a0 = (const float*)d_in[2];
    const float* a1 = (const float*)d_in[3];
    const int* row  = (const int*)d_in[4];
    const int* col  = (const int*)d_in[5];
    float* out = (float*)d_out;

    // Workspace layout (4B units):
    // [minmax: 64][gcount: 2048][s0: 50048][s1: 50048][Xp: 1.6M][gEdges: NB*CAP uint2]
    float* ws = (float*)d_ws;
    int*   minmax = (int*)ws;
    int*   gcount = (int*)(ws + 64);
    float* s0 = ws + 64 + 2048;
    float* s1 = s0 + 50048;
    float* Xp = s1 + 50048;  // 16B-aligned offset
    uint2* gEdges = (uint2*)(Xp + (size_t)N_NODES * D_OUT);

    k_xw<<<N_NODES / 8, 256, 0, stream>>>(X, W, a0, a1, Xp, s0, s1, minmax, gcount);
    k_part<<<(N_EDGES + EB - 1) / EB, PB, 0, stream>>>(row, col, s0, s1, gcount,
                                                       minmax, gEdges);
    k_bucket<<<NB, 256, 0, stream>>>(gcount, gEdges, Xp, minmax, out);
}